// Round 6
// baseline (719.619 us; speedup 1.0000x reference)
//
#include <hip/hip_runtime.h>

constexpr int N = 4;
constexpr int C = 64;
constexpr int H = 256;
constexpr int W = 448;
constexpr int HW = H * W;

// 8x8 bins (one wave owns one bin)
constexpr int BS = 8;
constexpr int BW_ = W / BS;            // 56
constexpr int BH_ = H / BS;            // 32
constexpr int BINS_PB = BW_ * BH_;     // 1792 per batch
constexpr int BINS = N * BINS_PB;      // 7168

// ===================== GATHER PATH (R5, resubmitted R6) =====================
// R5 bench died with "container failed twice" (infra, no kernel signal).
// Audit found no OOB/hang/graph-capture hazard; resubmitting unchanged to
// preserve attribution for the R5 theory:
// R4 post-mortem: VGPR-accum gather worked (657->206us). Remaining gather
// waste: 4 waves/block each scan the whole 16x16-tile list, 69% bbox-reject
// -> 2.08M latency-bound skip iterations. R5 bins at 8x8 (wave granularity):
// zero rejects, ~581K iterations, each with 128 cyc of FMA to hide loads.
// Pre-pass: count (flow-only) -> scan -> prepfill (aug + records in one pass).

__device__ __forceinline__ int binsOf(int x0, int y0, int bins[4]) {
    const int x1 = x0 + 1, y1 = y0 + 1;
    int n = 0;
    int bxA = -2, bxB = -2, byA = -2, byB = -2;
    if ((unsigned)x0 < (unsigned)W) bxA = x0 >> 3;
    if ((unsigned)x1 < (unsigned)W) { const int t = x1 >> 3; if (t != bxA) bxB = t; }
    if ((unsigned)y0 < (unsigned)H) byA = y0 >> 3;
    if ((unsigned)y1 < (unsigned)H) { const int t = y1 >> 3; if (t != byA) byB = t; }
    if (byA >= 0) {
        if (bxA >= 0) bins[n++] = byA * BW_ + bxA;
        if (bxB >= 0) bins[n++] = byA * BW_ + bxB;
    }
    if (byB >= 0) {
        if (bxA >= 0) bins[n++] = byB * BW_ + bxA;
        if (bxB >= 0) bins[n++] = byB * BW_ + bxB;
    }
    return n;
}

// count: flow-only pass, LDS-aggregated per-batch bin counts.
__global__ __launch_bounds__(1024) void count_kernel(
    const float* __restrict__ flow,
    unsigned* __restrict__ counts)    // [BINS]
{
    __shared__ unsigned lcnt[BINS_PB];
    const int tid = threadIdx.x;
    const int idx = blockIdx.x * 1024 + tid;     // HW % 1024 == 0
    const int b = idx / HW;
    const int p = idx - b * HW;
    const int y = p / W;
    const int x = p - y * W;

    for (int i = tid; i < BINS_PB; i += 1024) lcnt[i] = 0;
    __syncthreads();

    const float fx = (float)x + flow[(b * 2 + 0) * HW + p];
    const float fy = (float)y + flow[(b * 2 + 1) * HW + p];
    const int x0 = (int)floorf(fx), y0 = (int)floorf(fy);

    int bn[4];
    const int nb = binsOf(x0, y0, bn);
    for (int i = 0; i < nb; ++i) atomicAdd(&lcnt[bn[i]], 1u);
    __syncthreads();

    for (int i = tid; i < BINS_PB; i += 1024)
        if (lcnt[i]) atomicAdd(&counts[b * BINS_PB + i], lcnt[i]);
}

// scan: exclusive prefix sum of 7168 counts (= 1024*7), clamped at capE.
__global__ __launch_bounds__(1024) void scan_kernel(
    const unsigned* __restrict__ counts,
    unsigned* __restrict__ segstart,  // [BINS+1]
    unsigned capE)
{
    __shared__ unsigned lsum[1024];
    const int tid = threadIdx.x;
    unsigned v[7];
    unsigned s = 0;
#pragma unroll
    for (int i = 0; i < 7; ++i) { v[i] = counts[tid * 7 + i]; s += v[i]; }
    lsum[tid] = s;
    __syncthreads();
    for (int off = 1; off < 1024; off <<= 1) {
        const unsigned t = (tid >= off) ? lsum[tid - off] : 0u;
        __syncthreads();
        lsum[tid] += t;
        __syncthreads();
    }
    unsigned run = lsum[tid] - s;
#pragma unroll
    for (int i = 0; i < 7; ++i) {
        segstart[tid * 7 + i] = run < capE ? run : capE;
        run += v[i];
    }
    if (tid == 1023) segstart[BINS] = run < capE ? run : capE;
}

// prepfill: single big pass. input NCHW -> aug NHWC (premultiplied by m),
// and write 16-B records {fx,fy,m,bitcast(p)} into per-bin segments.
// Direct global cursor atomics: ~82 serialized RMW per address, negligible.
__global__ __launch_bounds__(256) void prepfill_kernel(
    const float* __restrict__ input,
    const float* __restrict__ flow,
    const float* __restrict__ metric,
    const unsigned* __restrict__ segstart,
    unsigned* __restrict__ cursor,    // [BINS], pre-zeroed
    float4* __restrict__ recs,        // [capE]
    float* __restrict__ aug,          // [N*HW][64]
    unsigned capE)
{
    __shared__ float s_val[128][65];
    __shared__ float s_m[128];

    const int tid = threadIdx.x;
    const int blockPix = blockIdx.x * 128;       // HW % 128 == 0
    const int b = blockPix / HW;
    const int pb = blockPix - b * HW;

    if (tid < 128) {
        const int p = pb + tid;
        const int y = p / W;
        const int x = p - y * W;
        const float fx = (float)x + flow[(b * 2 + 0) * HW + p];
        const float fy = (float)y + flow[(b * 2 + 1) * HW + p];
        const float m = __expf(metric[b * HW + p]);
        s_m[tid] = m;

        const int x0 = (int)floorf(fx), y0 = (int)floorf(fy);
        int bn[4];
        const int nb = binsOf(x0, y0, bn);
        const float4 rec = make_float4(fx, fy, m, __int_as_float(p));
        const int tb = b * BINS_PB;
        for (int i = 0; i < nb; ++i) {
            const unsigned off = atomicAdd(&cursor[tb + bn[i]], 1u);
            const unsigned slot = segstart[tb + bn[i]] + off;
            if (slot < capE) recs[slot] = rec;
        }
    }

    {
        const int sp = tid & 127;
        const int sc = tid >> 7;
        const float* ib = input + (size_t)b * C * HW + pb + sp;
#pragma unroll
        for (int c = 0; c < 32; ++c) {
            const int ch = 2 * c + sc;
            s_val[sp][ch] = ib[(size_t)ch * HW];
        }
    }
    __syncthreads();

    const int wv = tid >> 6, ln = tid & 63;
    float* abase = aug + ((size_t)b * HW + pb) * 64;
#pragma unroll
    for (int it = 0; it < 32; ++it) {
        const int j = (wv << 5) + it;
        abase[(size_t)j * 64 + ln] = s_val[j][ln] * s_m[j];
    }
}

// gather3: grid = BINS/4 blocks x 256 threads; wave w owns bin swz*4+w.
// lane = pixel of the 8x8 bin, acc[64] = channels in VGPRs. Every entry in
// the wave's list touches its bin -> no rejects; 64 FMAs per iteration hide
// the next record fetch + aug-row scalar loads.
__global__ __launch_bounds__(256) void gather3(
    const float4* __restrict__ recs,
    const float* __restrict__ aug,
    const unsigned* __restrict__ segstart,
    float* __restrict__ out)
{
    const int tid  = threadIdx.x;
    const int wq   = tid >> 6;
    const int lane = tid & 63;

    // XCD-contiguous swizzle (grid 1792 % 8 == 0)
    const int nwg = gridDim.x;
    const int bid = blockIdx.x;
    const int swz = (bid & 7) * (nwg >> 3) + (bid >> 3);

    const int g   = swz * 4 + wq;                // global bin id
    const int b   = g / BINS_PB;
    const int bin = g - b * BINS_PB;
    const int by  = bin / BW_;
    const int bx  = bin - by * BW_;
    const int qx0 = bx * BS;
    const int qy0 = by * BS;

    const float X = (float)(qx0 + (lane & 7));
    const float Y = (float)(qy0 + (lane >> 3));

    float acc[64];
#pragma unroll
    for (int c = 0; c < 64; ++c) acc[c] = 0.0f;
    float nrm = 0.0f;

    const int start = (int)segstart[g];
    const int end   = (int)segstart[g + 1];
    const float* ab = aug + (size_t)b * HW * 64;

    float4 r = (start < end) ? recs[start]
                             : make_float4(0.0f, 0.0f, 0.0f, 0.0f);
    for (int e = start; e < end; ++e) {
        const float4 rn = (e + 1 < end) ? recs[e + 1]
                                        : make_float4(0.0f, 0.0f, 0.0f, 0.0f);
        const int p = __builtin_amdgcn_readfirstlane(__float_as_int(r.w));
        const float ax = fmaxf(1.0f - fabsf(r.x - X), 0.0f);
        const float ay = fmaxf(1.0f - fabsf(r.y - Y), 0.0f);
        const float w = ax * ay;
        nrm = fmaf(r.z, w, nrm);
        const float* vp = ab + (size_t)p * 64;   // uniform -> scalar loads
#pragma unroll
        for (int c = 0; c < 64; ++c)
            acc[c] = fmaf(vp[c], w, acc[c]);
        r = rn;
    }

    const float inv = (nrm == 0.0f) ? 1.0f : (1.0f / nrm);
    float* ob = out + (size_t)b * C * HW;
    const int loff = (qy0 + (lane >> 3)) * W + qx0 + (lane & 7);
#pragma unroll
    for (int c = 0; c < 64; ++c)
        ob[(size_t)c * HW + loff] = acc[c] * inv;
}

// ===================== MID TIER (R1 fast path) ==============================
__global__ __launch_bounds__(256) void splat_nhwc(
    const float* __restrict__ input,
    const float* __restrict__ flow,
    const float* __restrict__ metric,
    float* __restrict__ scr,
    float* __restrict__ norm)
{
    __shared__ float s_val[128][65];
    __shared__ float s_fx[128], s_fy[128], s_m[128];

    const int tid = threadIdx.x;
    const int nwg = gridDim.x;
    const int bid = blockIdx.x;
    const int swz = (bid & 7) * (nwg >> 3) + (bid >> 3);

    const int blockPix = swz * 128;
    const int b = blockPix / HW;
    const int pb = blockPix - b * HW;

    if (tid < 128) {
        const int p = pb + tid;
        const int y = p / W;
        const int x = p - y * W;
        s_fx[tid] = (float)x + flow[(b * 2 + 0) * HW + p];
        s_fy[tid] = (float)y + flow[(b * 2 + 1) * HW + p];
        s_m[tid]  = __expf(metric[b * HW + p]);
    }
    {
        const int sp = tid & 127;
        const int sc = tid >> 7;
        const float* ib = input + (size_t)b * C * HW + pb + sp;
#pragma unroll
        for (int c = 0; c < 32; ++c) {
            const int ch = 2 * c + sc;
            s_val[sp][ch] = ib[(size_t)ch * HW];
        }
    }
    __syncthreads();

    const int wave = tid >> 6;
    const int lane = tid & 63;
    float* __restrict__ sb = scr + (size_t)b * HW * 64;
    float* __restrict__ nb = norm + b * HW;

    for (int k = 0; k < 32; ++k) {
        const int j = (wave << 5) | k;
        const float fx = s_fx[j], fy = s_fy[j], m = s_m[j];
        const float v = s_val[j][lane] * m;

        const float x0f = floorf(fx), y0f = floorf(fy);
        const int x0 = (int)x0f, y0 = (int)y0f;
        const int x1 = x0 + 1,   y1 = y0 + 1;
        const float wx1 = fx - x0f, wx0 = 1.0f - wx1;
        const float wy1 = fy - y0f, wy0 = 1.0f - wy1;

        const bool vx0 = (x0 >= 0) & (x0 < W);
        const bool vx1 = (x1 >= 0) & (x1 < W);
        const bool vy0 = (y0 >= 0) & (y0 < H);
        const bool vy1 = (y1 >= 0) & (y1 < H);

        if (vx0 & vy0) {
            const float w = wx0 * wy0; const int t = y0 * W + x0;
            atomicAdd(sb + (size_t)t * 64 + lane, v * w);
            if (lane == 0) atomicAdd(nb + t, m * w);
        }
        if (vx1 & vy0) {
            const float w = wx1 * wy0; const int t = y0 * W + x1;
            atomicAdd(sb + (size_t)t * 64 + lane, v * w);
            if (lane == 0) atomicAdd(nb + t, m * w);
        }
        if (vx0 & vy1) {
            const float w = wx0 * wy1; const int t = y1 * W + x0;
            atomicAdd(sb + (size_t)t * 64 + lane, v * w);
            if (lane == 0) atomicAdd(nb + t, m * w);
        }
        if (vx1 & vy1) {
            const float w = wx1 * wy1; const int t = y1 * W + x1;
            atomicAdd(sb + (size_t)t * 64 + lane, v * w);
            if (lane == 0) atomicAdd(nb + t, m * w);
        }
    }
}

__global__ __launch_bounds__(256) void untranspose_norm(
    const float* __restrict__ scr,
    const float* __restrict__ norm,
    float* __restrict__ out)
{
    __shared__ float s_t[64][65];
    __shared__ float s_inv[64];

    const int tid = threadIdx.x;
    const int strips = HW / 64;
    const int b = blockIdx.x / strips;
    const int pblk = (blockIdx.x - b * strips) * 64;

    if (tid < 64) {
        float n = norm[b * HW + pblk + tid];
        s_inv[tid] = (n == 0.0f) ? 1.0f : (1.0f / n);
    }
    const float* sb = scr + ((size_t)b * HW + pblk) * 64;
#pragma unroll
    for (int r = 0; r < 16; ++r) {
        const int pr = r * 4 + (tid >> 6);
        const int c  = tid & 63;
        s_t[pr][c] = sb[(size_t)pr * 64 + c];
    }
    __syncthreads();

    float* ob = out + (size_t)b * C * HW + pblk;
#pragma unroll
    for (int r = 0; r < 16; ++r) {
        const int c   = r * 4 + (tid >> 6);
        const int pix = tid & 63;
        ob[(size_t)c * HW + pix] = s_t[pix][c] * s_inv[pix];
    }
}

// ===================== FALLBACK (naive) =====================================
__global__ void splat_kernel(const float* __restrict__ input,
                             const float* __restrict__ flow,
                             const float* __restrict__ metric,
                             float* __restrict__ out,
                             float* __restrict__ norm)
{
    int idx = blockIdx.x * blockDim.x + threadIdx.x;
    if (idx >= N * HW) return;
    int b = idx / HW;
    int p = idx - b * HW;
    int y = p / W;
    int x = p - y * W;

    float fx = (float)x + flow[(b * 2 + 0) * HW + p];
    float fy = (float)y + flow[(b * 2 + 1) * HW + p];
    float m  = __expf(metric[b * HW + p]);

    float x0f = floorf(fx), y0f = floorf(fy);
    int x0 = (int)x0f, y0 = (int)y0f;
    int x1 = x0 + 1,   y1 = y0 + 1;
    float wx1 = fx - x0f, wx0 = 1.0f - wx1;
    float wy1 = fy - y0f, wy0 = 1.0f - wy1;

    bool vx0 = (x0 >= 0) & (x0 < W);
    bool vx1 = (x1 >= 0) & (x1 < W);
    bool vy0 = (y0 >= 0) & (y0 < H);
    bool vy1 = (y1 >= 0) & (y1 < H);

    bool vNW = vx0 & vy0, vNE = vx1 & vy0, vSW = vx0 & vy1, vSE = vx1 & vy1;
    float wNW = wx0 * wy0, wNE = wx1 * wy0, wSW = wx0 * wy1, wSE = wx1 * wy1;
    int iNW = y0 * W + x0, iNE = y0 * W + x1, iSW = y1 * W + x0, iSE = y1 * W + x1;

    {
        float* nb = norm + b * HW;
        if (vNW) atomicAdd(nb + iNW, m * wNW);
        if (vNE) atomicAdd(nb + iNE, m * wNE);
        if (vSW) atomicAdd(nb + iSW, m * wSW);
        if (vSE) atomicAdd(nb + iSE, m * wSE);
    }

    const float* ib = input + (size_t)b * C * HW + p;
    float* ob = out + (size_t)b * C * HW;
#pragma unroll 4
    for (int c = 0; c < C; ++c) {
        float v = ib[(size_t)c * HW] * m;
        float* oc = ob + (size_t)c * HW;
        if (vNW) atomicAdd(oc + iNW, v * wNW);
        if (vNE) atomicAdd(oc + iNE, v * wNE);
        if (vSW) atomicAdd(oc + iSW, v * wSW);
        if (vSE) atomicAdd(oc + iSE, v * wSE);
    }
}

__global__ void norm_kernel(float* __restrict__ out,
                            const float* __restrict__ norm)
{
    int idx = blockIdx.x * blockDim.x + threadIdx.x;
    int total = N * C * HW / 4;
    if (idx >= total) return;

    int pixq = idx % (HW / 4);
    int bc   = idx / (HW / 4);
    int b    = bc / C;

    const float4* np4 = (const float4*)(norm + (size_t)b * HW);
    float4 n = np4[pixq];
    n.x = (n.x == 0.0f) ? 1.0f : n.x;
    n.y = (n.y == 0.0f) ? 1.0f : n.y;
    n.z = (n.z == 0.0f) ? 1.0f : n.z;
    n.w = (n.w == 0.0f) ? 1.0f : n.w;

    float4* o4 = (float4*)out;
    float4 v = o4[idx];
    v.x /= n.x; v.y /= n.y; v.z /= n.z; v.w /= n.w;
    o4[idx] = v;
}

// ============================================================================
extern "C" void kernel_launch(void* const* d_in, const int* in_sizes, int n_in,
                              void* d_out, int out_size, void* d_ws, size_t ws_size,
                              hipStream_t stream)
{
    const float* input  = (const float*)d_in[0];   // (4,64,256,448)
    const float* flow   = (const float*)d_in[1];   // (4,2,256,448)
    const float* metric = (const float*)d_in[2];   // (4,1,256,448)
    float* out = (float*)d_out;

    const size_t augBytes  = (size_t)N * HW * 64 * sizeof(float);   // 117.44 MB
    const size_t metaBytes = ((size_t)BINS * 2 + BINS + 1) * sizeof(unsigned);

    // Record-capacity tiers (16 B records). Expected usage ~1.27 * N*HW.
    const size_t capFull = (size_t)4 * N * HW;
    const size_t cap2x   = (size_t)2 * N * HW;
    const size_t cap15x  = (size_t)3 * N * HW / 2;

    auto need = [&](size_t capE) {
        return augBytes + capE * sizeof(float4) + metaBytes;
    };
    const size_t need_mid = augBytes + (size_t)N * HW * sizeof(float);

    size_t capE = 0;
    if      (ws_size >= need(capFull)) capE = capFull;
    else if (ws_size >= need(cap2x))   capE = cap2x;
    else if (ws_size >= need(cap15x))  capE = cap15x;

    if (capE) {
        float*    aug      = (float*)d_ws;
        float4*   recs     = (float4*)((char*)d_ws + augBytes);
        unsigned* counts   = (unsigned*)(recs + capE);
        unsigned* cursor   = counts + BINS;
        unsigned* segstart = cursor + BINS;

        hipMemsetAsync(counts, 0, 2 * BINS * sizeof(unsigned), stream);
        count_kernel<<<N * HW / 1024, 1024, 0, stream>>>(flow, counts);
        scan_kernel<<<1, 1024, 0, stream>>>(counts, segstart, (unsigned)capE);
        prepfill_kernel<<<N * HW / 128, 256, 0, stream>>>(input, flow, metric,
                                                          segstart, cursor, recs,
                                                          aug, (unsigned)capE);
        gather3<<<BINS / 4, 256, 0, stream>>>(recs, aug, segstart, out);
    } else if (ws_size >= need_mid) {
        float* scr  = (float*)d_ws;
        float* norm = scr + (size_t)N * HW * 64;
        hipMemsetAsync(scr, 0, need_mid, stream);

        splat_nhwc<<<N * HW / 128, 256, 0, stream>>>(input, flow, metric, scr, norm);
        untranspose_norm<<<N * (HW / 64), 256, 0, stream>>>(scr, norm, out);
    } else {
        float* norm = (float*)d_ws;
        hipMemsetAsync(out,  0, (size_t)N * C * HW * sizeof(float), stream);
        hipMemsetAsync(norm, 0, (size_t)N * HW * sizeof(float), stream);

        splat_kernel<<<(N * HW + 255) / 256, 256, 0, stream>>>(input, flow, metric, out, norm);
        int total = N * C * HW / 4;
        norm_kernel<<<(total + 255) / 256, 256, 0, stream>>>(out, norm);
    }
}

// Round 7
// 587.288 us; speedup vs baseline: 1.2253x; 1.2253x over previous
//
#include <hip/hip_runtime.h>

constexpr int N = 4;
constexpr int C = 64;
constexpr int H = 256;
constexpr int W = 448;
constexpr int HW = H * W;

// 16x4 bins (one wave owns one bin; 64 px; 16-px rows = 64B store segments)
constexpr int BSX = 16;
constexpr int BSY = 4;
constexpr int BW_ = W / BSX;           // 28
constexpr int BH_ = H / BSY;           // 64
constexpr int BINS_PB = BW_ * BH_;     // 1792 per batch
constexpr int BINS = N * BINS_PB;      // 7168

// ===================== GATHER PATH (R7) =====================================
// R6 post-mortem: gather3 (581K zero-reject iters) was 2.4x SLOWER than R4's
// gather2 -- ~2100 cyc/iteration = the uncovered serial chain record ->
// readfirstlane(p) -> wave-uniform 64-dword row load -> FMAs. gather2 was
// accidentally masked by 4 waves sharing one list (cache reuse). The uniform
// row load can't be double-buffered (64 SGPRs x2 > budget).
// R7 transposes the mapping: lane = CHANNEL. Row read = aug[p*64+lane] = one
// coalesced 256B VECTOR load per entry, double-buffered in 1 VGPR -> latency
// hidden under previous entry's 64 fmacs (acc[64] = pixels, static index).
// Norm: second tiny lane=pixel pass over L2-hot records into 1 scalar reg;
// applied on the LDS-transpose epilogue read side (values already lane=pixel).

__device__ __forceinline__ int binsOf(int x0, int y0, int bins[4]) {
    const int x1 = x0 + 1, y1 = y0 + 1;
    int n = 0;
    int bxA = -2, bxB = -2, byA = -2, byB = -2;
    if ((unsigned)x0 < (unsigned)W) bxA = x0 >> 4;
    if ((unsigned)x1 < (unsigned)W) { const int t = x1 >> 4; if (t != bxA) bxB = t; }
    if ((unsigned)y0 < (unsigned)H) byA = y0 >> 2;
    if ((unsigned)y1 < (unsigned)H) { const int t = y1 >> 2; if (t != byA) byB = t; }
    if (byA >= 0) {
        if (bxA >= 0) bins[n++] = byA * BW_ + bxA;
        if (bxB >= 0) bins[n++] = byA * BW_ + bxB;
    }
    if (byB >= 0) {
        if (bxA >= 0) bins[n++] = byB * BW_ + bxA;
        if (bxB >= 0) bins[n++] = byB * BW_ + bxB;
    }
    return n;
}

// count: flow-only pass, LDS-aggregated per-batch bin counts.
__global__ __launch_bounds__(1024) void count_kernel(
    const float* __restrict__ flow,
    unsigned* __restrict__ counts)    // [BINS]
{
    __shared__ unsigned lcnt[BINS_PB];
    const int tid = threadIdx.x;
    const int idx = blockIdx.x * 1024 + tid;     // HW % 1024 == 0
    const int b = idx / HW;
    const int p = idx - b * HW;
    const int y = p / W;
    const int x = p - y * W;

    for (int i = tid; i < BINS_PB; i += 1024) lcnt[i] = 0;
    __syncthreads();

    const float fx = (float)x + flow[(b * 2 + 0) * HW + p];
    const float fy = (float)y + flow[(b * 2 + 1) * HW + p];
    const int x0 = (int)floorf(fx), y0 = (int)floorf(fy);

    int bn[4];
    const int nb = binsOf(x0, y0, bn);
    for (int i = 0; i < nb; ++i) atomicAdd(&lcnt[bn[i]], 1u);
    __syncthreads();

    for (int i = tid; i < BINS_PB; i += 1024)
        if (lcnt[i]) atomicAdd(&counts[b * BINS_PB + i], lcnt[i]);
}

// scan: exclusive prefix sum of 7168 counts (= 1024*7), clamped at capE.
__global__ __launch_bounds__(1024) void scan_kernel(
    const unsigned* __restrict__ counts,
    unsigned* __restrict__ segstart,  // [BINS+1]
    unsigned capE)
{
    __shared__ unsigned lsum[1024];
    const int tid = threadIdx.x;
    unsigned v[7];
    unsigned s = 0;
#pragma unroll
    for (int i = 0; i < 7; ++i) { v[i] = counts[tid * 7 + i]; s += v[i]; }
    lsum[tid] = s;
    __syncthreads();
    for (int off = 1; off < 1024; off <<= 1) {
        const unsigned t = (tid >= off) ? lsum[tid - off] : 0u;
        __syncthreads();
        lsum[tid] += t;
        __syncthreads();
    }
    unsigned run = lsum[tid] - s;
#pragma unroll
    for (int i = 0; i < 7; ++i) {
        segstart[tid * 7 + i] = run < capE ? run : capE;
        run += v[i];
    }
    if (tid == 1023) segstart[BINS] = run < capE ? run : capE;
}

// prepfill: input NCHW -> aug NHWC (premultiplied by m), and write 16-B
// records {fx,fy,m,bitcast(p)} into per-bin segments.
__global__ __launch_bounds__(256) void prepfill_kernel(
    const float* __restrict__ input,
    const float* __restrict__ flow,
    const float* __restrict__ metric,
    const unsigned* __restrict__ segstart,
    unsigned* __restrict__ cursor,    // [BINS], pre-zeroed
    float4* __restrict__ recs,        // [capE]
    float* __restrict__ aug,          // [N*HW][64]
    unsigned capE)
{
    __shared__ float s_val[128][65];
    __shared__ float s_m[128];

    const int tid = threadIdx.x;
    const int blockPix = blockIdx.x * 128;       // HW % 128 == 0
    const int b = blockPix / HW;
    const int pb = blockPix - b * HW;

    if (tid < 128) {
        const int p = pb + tid;
        const int y = p / W;
        const int x = p - y * W;
        const float fx = (float)x + flow[(b * 2 + 0) * HW + p];
        const float fy = (float)y + flow[(b * 2 + 1) * HW + p];
        const float m = __expf(metric[b * HW + p]);
        s_m[tid] = m;

        const int x0 = (int)floorf(fx), y0 = (int)floorf(fy);
        int bn[4];
        const int nb = binsOf(x0, y0, bn);
        const float4 rec = make_float4(fx, fy, m, __int_as_float(p));
        const int tb = b * BINS_PB;
        for (int i = 0; i < nb; ++i) {
            const unsigned off = atomicAdd(&cursor[tb + bn[i]], 1u);
            const unsigned slot = segstart[tb + bn[i]] + off;
            if (slot < capE) recs[slot] = rec;
        }
    }

    {
        const int sp = tid & 127;
        const int sc = tid >> 7;
        const float* ib = input + (size_t)b * C * HW + pb + sp;
#pragma unroll
        for (int c = 0; c < 32; ++c) {
            const int ch = 2 * c + sc;
            s_val[sp][ch] = ib[(size_t)ch * HW];
        }
    }
    __syncthreads();

    const int wv = tid >> 6, ln = tid & 63;
    float* abase = aug + ((size_t)b * HW + pb) * 64;
#pragma unroll
    for (int it = 0; it < 32; ++it) {
        const int j = (wv << 5) + it;
        abase[(size_t)j * 64 + ln] = s_val[j][ln] * s_m[j];
    }
}

// gather4: grid = BINS/4 blocks x 256 threads; wave w owns bin swz*4+w.
// lane = CHANNEL; acc[64] = pixels of the 16x4 bin (static index).
// Per entry: one coalesced 256B vector row load (double-buffered) + hat
// weights axx[16]*ayy[4] + 64 fmacs. Norm: lane=pixel re-pass over records.
// Epilogue: shared 16.6KB LDS transpose (4 waves round-robin), coalesced out.
__global__ __launch_bounds__(256) void gather4(
    const float4* __restrict__ recs,
    const float* __restrict__ aug,
    const unsigned* __restrict__ segstart,
    float* __restrict__ out)
{
    __shared__ float st[64][65];      // 16.64 KB, shared round-robin by waves

    const int tid  = threadIdx.x;
    const int wq   = tid >> 6;
    const int lane = tid & 63;

    // XCD-contiguous swizzle (grid 1792 % 8 == 0)
    const int nwg = gridDim.x;
    const int bid = blockIdx.x;
    const int swz = (bid & 7) * (nwg >> 3) + (bid >> 3);

    const int g   = swz * 4 + wq;                // global bin id
    const int b   = g / BINS_PB;
    const int bin = g - b * BINS_PB;
    const int by  = bin / BW_;
    const int bx  = bin - by * BW_;
    const int qx0 = bx * BSX;
    const int qy0 = by * BSY;

    float acc[64];
#pragma unroll
    for (int i = 0; i < 64; ++i) acc[i] = 0.0f;

    const int start = (int)segstart[g];
    const int end   = (int)segstart[g + 1];
    const float* ab = aug + (size_t)b * HW * 64;

    // ---- main loop: lane = channel ----
    float4 r = make_float4(0.0f, 0.0f, 0.0f, 0.0f);
    float  v = 0.0f;
    if (start < end) {
        r = recs[start];
        const int p = __builtin_amdgcn_readfirstlane(__float_as_int(r.w));
        v = ab[(size_t)p * 64 + lane];
    }
    for (int e = start; e < end; ++e) {
        // issue next entry's record + row load (independent of current work)
        float4 rn = make_float4(0.0f, 0.0f, 0.0f, 0.0f);
        float  vn = 0.0f;
        if (e + 1 < end) {
            rn = recs[e + 1];
            const int pn = __builtin_amdgcn_readfirstlane(__float_as_int(rn.w));
            vn = ab[(size_t)pn * 64 + lane];
        }

        const float fxl = r.x - (float)qx0;
        const float fyl = r.y - (float)qy0;
        float axx[16], ayy[4];
#pragma unroll
        for (int i = 0; i < 16; ++i)
            axx[i] = fmaxf(1.0f - fabsf(fxl - (float)i), 0.0f);
#pragma unroll
        for (int j = 0; j < 4; ++j)
            ayy[j] = fmaxf(1.0f - fabsf(fyl - (float)j), 0.0f);

        float tv[4];
#pragma unroll
        for (int j = 0; j < 4; ++j) tv[j] = v * ayy[j];
#pragma unroll
        for (int j = 0; j < 4; ++j)
#pragma unroll
            for (int i = 0; i < 16; ++i)
                acc[j * 16 + i] = fmaf(tv[j], axx[i], acc[j * 16 + i]);

        r = rn; v = vn;
    }

    // ---- norm pass: lane = pixel, records are L2-hot ----
    const int pxx = lane & 15, pyy = lane >> 4;
    const float Xp = (float)(qx0 + pxx);
    const float Yp = (float)(qy0 + pyy);
    float nrm = 0.0f;
    float4 r2 = make_float4(0.0f, 0.0f, 0.0f, 0.0f);
    if (start < end) r2 = recs[start];
    for (int e = start; e < end; ++e) {
        const float4 r2n = (e + 1 < end) ? recs[e + 1]
                                         : make_float4(0.0f, 0.0f, 0.0f, 0.0f);
        const float ax = fmaxf(1.0f - fabsf(r2.x - Xp), 0.0f);
        const float ay = fmaxf(1.0f - fabsf(r2.y - Yp), 0.0f);
        nrm = fmaf(r2.z, ax * ay, nrm);
        r2 = r2n;
    }
    const float inv = (nrm == 0.0f) ? 1.0f : (1.0f / nrm);

    // ---- epilogue: transpose via shared LDS buffer, 4 waves round-robin ----
    float* ob = out + (size_t)b * C * HW;
    const int ooff = (qy0 + pyy) * W + qx0 + pxx;   // lane = pixel
    for (int turn = 0; turn < 4; ++turn) {
        if (wq == turn) {
#pragma unroll
            for (int px = 0; px < 64; ++px) st[px][lane] = acc[px];  // lane=ch
            asm volatile("s_waitcnt lgkmcnt(0)" ::: "memory");
#pragma unroll
            for (int c = 0; c < 64; ++c)                             // lane=px
                ob[(size_t)c * HW + ooff] = st[lane][c] * inv;
        }
        __syncthreads();
    }
}

// ===================== MID TIER (R1 fast path) ==============================
__global__ __launch_bounds__(256) void splat_nhwc(
    const float* __restrict__ input,
    const float* __restrict__ flow,
    const float* __restrict__ metric,
    float* __restrict__ scr,
    float* __restrict__ norm)
{
    __shared__ float s_val[128][65];
    __shared__ float s_fx[128], s_fy[128], s_m[128];

    const int tid = threadIdx.x;
    const int nwg = gridDim.x;
    const int bid = blockIdx.x;
    const int swz = (bid & 7) * (nwg >> 3) + (bid >> 3);

    const int blockPix = swz * 128;
    const int b = blockPix / HW;
    const int pb = blockPix - b * HW;

    if (tid < 128) {
        const int p = pb + tid;
        const int y = p / W;
        const int x = p - y * W;
        s_fx[tid] = (float)x + flow[(b * 2 + 0) * HW + p];
        s_fy[tid] = (float)y + flow[(b * 2 + 1) * HW + p];
        s_m[tid]  = __expf(metric[b * HW + p]);
    }
    {
        const int sp = tid & 127;
        const int sc = tid >> 7;
        const float* ib = input + (size_t)b * C * HW + pb + sp;
#pragma unroll
        for (int c = 0; c < 32; ++c) {
            const int ch = 2 * c + sc;
            s_val[sp][ch] = ib[(size_t)ch * HW];
        }
    }
    __syncthreads();

    const int wave = tid >> 6;
    const int lane = tid & 63;
    float* __restrict__ sb = scr + (size_t)b * HW * 64;
    float* __restrict__ nb = norm + b * HW;

    for (int k = 0; k < 32; ++k) {
        const int j = (wave << 5) | k;
        const float fx = s_fx[j], fy = s_fy[j], m = s_m[j];
        const float v = s_val[j][lane] * m;

        const float x0f = floorf(fx), y0f = floorf(fy);
        const int x0 = (int)x0f, y0 = (int)y0f;
        const int x1 = x0 + 1,   y1 = y0 + 1;
        const float wx1 = fx - x0f, wx0 = 1.0f - wx1;
        const float wy1 = fy - y0f, wy0 = 1.0f - wy1;

        const bool vx0 = (x0 >= 0) & (x0 < W);
        const bool vx1 = (x1 >= 0) & (x1 < W);
        const bool vy0 = (y0 >= 0) & (y0 < H);
        const bool vy1 = (y1 >= 0) & (y1 < H);

        if (vx0 & vy0) {
            const float w = wx0 * wy0; const int t = y0 * W + x0;
            atomicAdd(sb + (size_t)t * 64 + lane, v * w);
            if (lane == 0) atomicAdd(nb + t, m * w);
        }
        if (vx1 & vy0) {
            const float w = wx1 * wy0; const int t = y0 * W + x1;
            atomicAdd(sb + (size_t)t * 64 + lane, v * w);
            if (lane == 0) atomicAdd(nb + t, m * w);
        }
        if (vx0 & vy1) {
            const float w = wx0 * wy1; const int t = y1 * W + x0;
            atomicAdd(sb + (size_t)t * 64 + lane, v * w);
            if (lane == 0) atomicAdd(nb + t, m * w);
        }
        if (vx1 & vy1) {
            const float w = wx1 * wy1; const int t = y1 * W + x1;
            atomicAdd(sb + (size_t)t * 64 + lane, v * w);
            if (lane == 0) atomicAdd(nb + t, m * w);
        }
    }
}

__global__ __launch_bounds__(256) void untranspose_norm(
    const float* __restrict__ scr,
    const float* __restrict__ norm,
    float* __restrict__ out)
{
    __shared__ float s_t[64][65];
    __shared__ float s_inv[64];

    const int tid = threadIdx.x;
    const int strips = HW / 64;
    const int b = blockIdx.x / strips;
    const int pblk = (blockIdx.x - b * strips) * 64;

    if (tid < 64) {
        float n = norm[b * HW + pblk + tid];
        s_inv[tid] = (n == 0.0f) ? 1.0f : (1.0f / n);
    }
    const float* sb = scr + ((size_t)b * HW + pblk) * 64;
#pragma unroll
    for (int r = 0; r < 16; ++r) {
        const int pr = r * 4 + (tid >> 6);
        const int c  = tid & 63;
        s_t[pr][c] = sb[(size_t)pr * 64 + c];
    }
    __syncthreads();

    float* ob = out + (size_t)b * C * HW + pblk;
#pragma unroll
    for (int r = 0; r < 16; ++r) {
        const int c   = r * 4 + (tid >> 6);
        const int pix = tid & 63;
        ob[(size_t)c * HW + pix] = s_t[pix][c] * s_inv[pix];
    }
}

// ===================== FALLBACK (naive) =====================================
__global__ void splat_kernel(const float* __restrict__ input,
                             const float* __restrict__ flow,
                             const float* __restrict__ metric,
                             float* __restrict__ out,
                             float* __restrict__ norm)
{
    int idx = blockIdx.x * blockDim.x + threadIdx.x;
    if (idx >= N * HW) return;
    int b = idx / HW;
    int p = idx - b * HW;
    int y = p / W;
    int x = p - y * W;

    float fx = (float)x + flow[(b * 2 + 0) * HW + p];
    float fy = (float)y + flow[(b * 2 + 1) * HW + p];
    float m  = __expf(metric[b * HW + p]);

    float x0f = floorf(fx), y0f = floorf(fy);
    int x0 = (int)x0f, y0 = (int)y0f;
    int x1 = x0 + 1,   y1 = y0 + 1;
    float wx1 = fx - x0f, wx0 = 1.0f - wx1;
    float wy1 = fy - y0f, wy0 = 1.0f - wy1;

    bool vx0 = (x0 >= 0) & (x0 < W);
    bool vx1 = (x1 >= 0) & (x1 < W);
    bool vy0 = (y0 >= 0) & (y0 < H);
    bool vy1 = (y1 >= 0) & (y1 < H);

    bool vNW = vx0 & vy0, vNE = vx1 & vy0, vSW = vx0 & vy1, vSE = vx1 & vy1;
    float wNW = wx0 * wy0, wNE = wx1 * wy0, wSW = wx0 * wy1, wSE = wx1 * wy1;
    int iNW = y0 * W + x0, iNE = y0 * W + x1, iSW = y1 * W + x0, iSE = y1 * W + x1;

    {
        float* nb = norm + b * HW;
        if (vNW) atomicAdd(nb + iNW, m * wNW);
        if (vNE) atomicAdd(nb + iNE, m * wNE);
        if (vSW) atomicAdd(nb + iSW, m * wSW);
        if (vSE) atomicAdd(nb + iSE, m * wSE);
    }

    const float* ib = input + (size_t)b * C * HW + p;
    float* ob = out + (size_t)b * C * HW;
#pragma unroll 4
    for (int c = 0; c < C; ++c) {
        float v = ib[(size_t)c * HW] * m;
        float* oc = ob + (size_t)c * HW;
        if (vNW) atomicAdd(oc + iNW, v * wNW);
        if (vNE) atomicAdd(oc + iNE, v * wNE);
        if (vSW) atomicAdd(oc + iSW, v * wSW);
        if (vSE) atomicAdd(oc + iSE, v * wSE);
    }
}

__global__ void norm_kernel(float* __restrict__ out,
                            const float* __restrict__ norm)
{
    int idx = blockIdx.x * blockDim.x + threadIdx.x;
    int total = N * C * HW / 4;
    if (idx >= total) return;

    int pixq = idx % (HW / 4);
    int bc   = idx / (HW / 4);
    int b    = bc / C;

    const float4* np4 = (const float4*)(norm + (size_t)b * HW);
    float4 n = np4[pixq];
    n.x = (n.x == 0.0f) ? 1.0f : n.x;
    n.y = (n.y == 0.0f) ? 1.0f : n.y;
    n.z = (n.z == 0.0f) ? 1.0f : n.z;
    n.w = (n.w == 0.0f) ? 1.0f : n.w;

    float4* o4 = (float4*)out;
    float4 v = o4[idx];
    v.x /= n.x; v.y /= n.y; v.z /= n.z; v.w /= n.w;
    o4[idx] = v;
}

// ============================================================================
extern "C" void kernel_launch(void* const* d_in, const int* in_sizes, int n_in,
                              void* d_out, int out_size, void* d_ws, size_t ws_size,
                              hipStream_t stream)
{
    const float* input  = (const float*)d_in[0];   // (4,64,256,448)
    const float* flow   = (const float*)d_in[1];   // (4,2,256,448)
    const float* metric = (const float*)d_in[2];   // (4,1,256,448)
    float* out = (float*)d_out;

    const size_t augBytes  = (size_t)N * HW * 64 * sizeof(float);   // 117.44 MB
    const size_t metaBytes = ((size_t)BINS * 2 + BINS + 1) * sizeof(unsigned);

    // Record-capacity tiers (16 B records). Expected usage ~1.33 * N*HW.
    const size_t capFull = (size_t)4 * N * HW;
    const size_t cap2x   = (size_t)2 * N * HW;
    const size_t cap15x  = (size_t)3 * N * HW / 2;

    auto need = [&](size_t capE) {
        return augBytes + capE * sizeof(float4) + metaBytes;
    };
    const size_t need_mid = augBytes + (size_t)N * HW * sizeof(float);

    size_t capE = 0;
    if      (ws_size >= need(capFull)) capE = capFull;
    else if (ws_size >= need(cap2x))   capE = cap2x;
    else if (ws_size >= need(cap15x))  capE = cap15x;

    if (capE) {
        float*    aug      = (float*)d_ws;
        float4*   recs     = (float4*)((char*)d_ws + augBytes);
        unsigned* counts   = (unsigned*)(recs + capE);
        unsigned* cursor   = counts + BINS;
        unsigned* segstart = cursor + BINS;

        hipMemsetAsync(counts, 0, 2 * BINS * sizeof(unsigned), stream);
        count_kernel<<<N * HW / 1024, 1024, 0, stream>>>(flow, counts);
        scan_kernel<<<1, 1024, 0, stream>>>(counts, segstart, (unsigned)capE);
        prepfill_kernel<<<N * HW / 128, 256, 0, stream>>>(input, flow, metric,
                                                          segstart, cursor, recs,
                                                          aug, (unsigned)capE);
        gather4<<<BINS / 4, 256, 0, stream>>>(recs, aug, segstart, out);
    } else if (ws_size >= need_mid) {
        float* scr  = (float*)d_ws;
        float* norm = scr + (size_t)N * HW * 64;
        hipMemsetAsync(scr, 0, need_mid, stream);

        splat_nhwc<<<N * HW / 128, 256, 0, stream>>>(input, flow, metric, scr, norm);
        untranspose_norm<<<N * (HW / 64), 256, 0, stream>>>(scr, norm, out);
    } else {
        float* norm = (float*)d_ws;
        hipMemsetAsync(out,  0, (size_t)N * C * HW * sizeof(float), stream);
        hipMemsetAsync(norm, 0, (size_t)N * HW * sizeof(float), stream);

        splat_kernel<<<(N * HW + 255) / 256, 256, 0, stream>>>(input, flow, metric, out, norm);
        int total = N * C * HW / 4;
        norm_kernel<<<(total + 255) / 256, 256, 0, stream>>>(out, norm);
    }
}